// Round 1
// baseline (777.154 us; speedup 1.0000x reference)
//
#include <hip/hip_runtime.h>

#define BB 8
#define SS 2048
#define HH 3584
#define EE 8
#define RR 16
#define KK 2
#define KR 32          // K*R combined axis, kr = k*16 + r
#define SCALE 2.0f     // lora_alpha / lora_r

// ---------------------------------------------------------------------------
// Phase 1: low[b][s][kr] += sum_{h in block's slice} x[b][s][h] * A[e_k][r][h]
// grid (hsplit=14, stile=8, b=8), block = 128 threads (2 waves)
// Each block: 256 s-rows x 32 kr x 256 h-columns, accumulated via atomicAdd.
// thread = (sg 0..31, krg 0..3): owns rows sg + i*32 (i<8), kr = krg*8+j (j<8)
// ---------------------------------------------------------------------------
#define P1_TS   256
#define P1_CH   32
#define P1_HS   256
#define P1_XPAD 36
#define P1_APAD 36

__global__ __launch_bounds__(128) void lora_low_kernel(
    const float* __restrict__ x, const float* __restrict__ lora_A,
    const int* __restrict__ topk_idx, float* __restrict__ low)
{
    __shared__ float xt[P1_TS * P1_XPAD];   // [row][h_local], pad 36
    __shared__ float at[P1_CH * P1_APAD];   // [h_local][kr],  pad 36

    const int tid = threadIdx.x;
    const int b   = blockIdx.z;
    const int s0  = blockIdx.y * P1_TS;
    const int h0  = blockIdx.x * P1_HS;

    const int krg = tid & 3;    // 0..3  -> kr base = krg*8
    const int sg  = tid >> 2;   // 0..31 -> rows sg + i*32

    const int e0 = topk_idx[b * KK + 0];
    const int e1 = topk_idx[b * KK + 1];

    float acc[8][8];
    #pragma unroll
    for (int i = 0; i < 8; ++i)
        #pragma unroll
        for (int j = 0; j < 8; ++j) acc[i][j] = 0.0f;

    for (int c = 0; c < P1_HS / P1_CH; ++c) {
        const int hc = h0 + c * P1_CH;

        // ---- stage x tile: 256 rows x 32 cols, float4 loads ----
        #pragma unroll
        for (int it = 0; it < 16; ++it) {
            const int row = it * 16 + (tid >> 3);
            const int col = (tid & 7) * 4;
            const float4 v = *reinterpret_cast<const float4*>(
                x + ((size_t)(b * SS + s0 + row)) * HH + hc + col);
            *reinterpret_cast<float4*>(&xt[row * P1_XPAD + col]) = v;
        }

        // ---- stage A tile transposed: at[h_local][kr] ----
        #pragma unroll
        for (int it = 0; it < 2; ++it) {
            const int id4 = it * 128 + tid;        // 0..255 float4s
            const int kr  = id4 >> 3;              // 0..31
            const int h4  = id4 & 7;               // 0..7
            const int e   = (kr < 16) ? e0 : e1;
            const int r   = kr & 15;
            const float4 v = *reinterpret_cast<const float4*>(
                lora_A + ((size_t)(e * RR + r)) * HH + hc + h4 * 4);
            at[(h4 * 4 + 0) * P1_APAD + kr] = v.x;
            at[(h4 * 4 + 1) * P1_APAD + kr] = v.y;
            at[(h4 * 4 + 2) * P1_APAD + kr] = v.z;
            at[(h4 * 4 + 3) * P1_APAD + kr] = v.w;
        }

        __syncthreads();

        // ---- compute: 32 h-steps, 64 FMA each ----
        #pragma unroll 4
        for (int hh = 0; hh < P1_CH; ++hh) {
            const float4 a0 = *reinterpret_cast<const float4*>(
                &at[hh * P1_APAD + krg * 8]);
            const float4 a1 = *reinterpret_cast<const float4*>(
                &at[hh * P1_APAD + krg * 8 + 4]);
            #pragma unroll
            for (int i = 0; i < 8; ++i) {
                const float xv = xt[(sg + i * 32) * P1_XPAD + hh];
                acc[i][0] = fmaf(xv, a0.x, acc[i][0]);
                acc[i][1] = fmaf(xv, a0.y, acc[i][1]);
                acc[i][2] = fmaf(xv, a0.z, acc[i][2]);
                acc[i][3] = fmaf(xv, a0.w, acc[i][3]);
                acc[i][4] = fmaf(xv, a1.x, acc[i][4]);
                acc[i][5] = fmaf(xv, a1.y, acc[i][5]);
                acc[i][6] = fmaf(xv, a1.z, acc[i][6]);
                acc[i][7] = fmaf(xv, a1.w, acc[i][7]);
            }
        }

        __syncthreads();
    }

    // ---- split-H reduction via fp32 atomics (14 contributions/element) ----
    float* lp = low + ((size_t)(b * SS + s0)) * KR;
    #pragma unroll
    for (int i = 0; i < 8; ++i) {
        const int srow = sg + i * 32;
        #pragma unroll
        for (int j = 0; j < 8; ++j)
            atomicAdd(&lp[srow * KR + krg * 8 + j], acc[i][j]);
    }
}

// ---------------------------------------------------------------------------
// Phase 2: out[b][s][h] = base[b][s][h] + sum_kr low[b][s][kr] * beff[h][kr]
//          beff[h][k*16+r] = SCALE * w[b][k] * lora_B[e_k][h][r]
// grid (htile=28, stile=16, b=8), block = 256 threads (4 waves)
// tile 128 s x 128 h; thread = (sy 0..15, hx 0..15):
//   rows sy + i*16 (i<8, interleaved), cols hx*8 + j (contiguous for float4)
// ---------------------------------------------------------------------------
#define P2_TS   128
#define P2_TH   128
#define P2_LPAD 36
#define P2_BPAD 132

__global__ __launch_bounds__(256) void lora_apply_kernel(
    const float* __restrict__ base, const float* __restrict__ lora_B,
    const float* __restrict__ topk_w, const int* __restrict__ topk_idx,
    const float* __restrict__ low, float* __restrict__ out)
{
    __shared__ float lt[P2_TS * P2_LPAD];   // [s_local][kr], pad 36
    __shared__ float bt[KR * P2_BPAD];      // [kr][h_local], pad 132

    const int tid = threadIdx.x;
    const int b   = blockIdx.z;
    const int s0  = blockIdx.y * P2_TS;
    const int h0  = blockIdx.x * P2_TH;

    const int sy = tid >> 4;   // 0..15
    const int hx = tid & 15;   // 0..15

    // ---- stage low tile: 128 rows x 32 kr ----
    #pragma unroll
    for (int it = 0; it < 4; ++it) {
        const int id4 = it * 256 + tid;    // 0..1023 float4s
        const int row = id4 >> 3;          // 0..127
        const int k4  = id4 & 7;           // 0..7
        const float4 v = *reinterpret_cast<const float4*>(
            low + ((size_t)(b * SS + s0 + row)) * KR + k4 * 4);
        *reinterpret_cast<float4*>(&lt[row * P2_LPAD + k4 * 4]) = v;
    }

    // ---- stage beff transposed: bt[kr][h_local] with gate*SCALE folded ----
    #pragma unroll
    for (int k = 0; k < KK; ++k) {
        const int   e  = topk_idx[b * KK + k];
        const float ww = topk_w[b * KK + k] * SCALE;
        #pragma unroll
        for (int it = 0; it < 2; ++it) {
            const int id4 = it * 256 + tid;    // 0..511 float4s
            const int hh  = id4 >> 2;          // 0..127
            const int r4  = id4 & 3;           // 0..3
            const float4 v = *reinterpret_cast<const float4*>(
                lora_B + ((size_t)(e * HH + h0 + hh)) * RR + r4 * 4);
            bt[(k * 16 + r4 * 4 + 0) * P2_BPAD + hh] = v.x * ww;
            bt[(k * 16 + r4 * 4 + 1) * P2_BPAD + hh] = v.y * ww;
            bt[(k * 16 + r4 * 4 + 2) * P2_BPAD + hh] = v.z * ww;
            bt[(k * 16 + r4 * 4 + 3) * P2_BPAD + hh] = v.w * ww;
        }
    }

    __syncthreads();

    // ---- init accumulators from base (epilogue add folded into init) ----
    const float* bp = base + ((size_t)(b * SS + s0)) * HH + h0;
    float*       op = out  + ((size_t)(b * SS + s0)) * HH + h0;

    float acc[8][8];
    #pragma unroll
    for (int i = 0; i < 8; ++i) {
        const size_t off = (size_t)(sy + i * 16) * HH + hx * 8;
        const float4 c0 = *reinterpret_cast<const float4*>(bp + off);
        const float4 c1 = *reinterpret_cast<const float4*>(bp + off + 4);
        acc[i][0] = c0.x; acc[i][1] = c0.y; acc[i][2] = c0.z; acc[i][3] = c0.w;
        acc[i][4] = c1.x; acc[i][5] = c1.y; acc[i][6] = c1.z; acc[i][7] = c1.w;
    }

    // ---- rank-32 update ----
    #pragma unroll 4
    for (int kr = 0; kr < KR; ++kr) {
        const float4 b0 = *reinterpret_cast<const float4*>(
            &bt[kr * P2_BPAD + hx * 8]);
        const float4 b1 = *reinterpret_cast<const float4*>(
            &bt[kr * P2_BPAD + hx * 8 + 4]);
        #pragma unroll
        for (int i = 0; i < 8; ++i) {
            const float lv = lt[(sy + i * 16) * P2_LPAD + kr];
            acc[i][0] = fmaf(lv, b0.x, acc[i][0]);
            acc[i][1] = fmaf(lv, b0.y, acc[i][1]);
            acc[i][2] = fmaf(lv, b0.z, acc[i][2]);
            acc[i][3] = fmaf(lv, b0.w, acc[i][3]);
            acc[i][4] = fmaf(lv, b1.x, acc[i][4]);
            acc[i][5] = fmaf(lv, b1.y, acc[i][5]);
            acc[i][6] = fmaf(lv, b1.z, acc[i][6]);
            acc[i][7] = fmaf(lv, b1.w, acc[i][7]);
        }
    }

    // ---- store ----
    #pragma unroll
    for (int i = 0; i < 8; ++i) {
        const size_t off = (size_t)(sy + i * 16) * HH + hx * 8;
        float4 c0, c1;
        c0.x = acc[i][0]; c0.y = acc[i][1]; c0.z = acc[i][2]; c0.w = acc[i][3];
        c1.x = acc[i][4]; c1.y = acc[i][5]; c1.z = acc[i][6]; c1.w = acc[i][7];
        *reinterpret_cast<float4*>(op + off)     = c0;
        *reinterpret_cast<float4*>(op + off + 4) = c1;
    }
}

// ---------------------------------------------------------------------------
extern "C" void kernel_launch(void* const* d_in, const int* in_sizes, int n_in,
                              void* d_out, int out_size, void* d_ws, size_t ws_size,
                              hipStream_t stream)
{
    const float* x      = (const float*)d_in[0];
    const float* base   = (const float*)d_in[1];
    const float* lora_A = (const float*)d_in[2];
    const float* lora_B = (const float*)d_in[3];
    const float* topk_w = (const float*)d_in[4];
    const int*   tk_idx = (const int*)d_in[5];
    float*       out    = (float*)d_out;
    float*       low    = (float*)d_ws;   // B*S*32 fp32 = 2 MB

    // ws is re-poisoned before every timed launch -> zero it every call.
    hipMemsetAsync(low, 0, (size_t)BB * SS * KR * sizeof(float), stream);

    dim3 g1(HH / P1_HS, SS / P1_TS, BB);   // (14, 8, 8)
    lora_low_kernel<<<g1, 128, 0, stream>>>(x, lora_A, tk_idx, low);

    dim3 g2(HH / P2_TH, SS / P2_TS, BB);   // (28, 16, 8)
    lora_apply_kernel<<<g2, 256, 0, stream>>>(base, lora_B, topk_w, tk_idx, low, out);
}